// Round 1
// 1301.811 us; speedup vs baseline: 1.2354x; 1.2354x over previous
//
#include <hip/hip_runtime.h>

constexpr int NFEAT = 1024;
constexpr int HID   = 64;
constexpr int NC    = 16;

typedef __attribute__((ext_vector_type(8))) short bf16x8;
typedef __attribute__((ext_vector_type(4))) float f32x4;

__device__ inline unsigned short f2bf(float f) {
  unsigned u = __float_as_uint(f);
  unsigned r = u + 0x7FFFu + ((u >> 16) & 1u);
  return (unsigned short)(r >> 16);
}

// ---------------- bucket-level histogram (row>>8), LDS-staged ----------------
// replaces the per-row global-atomic k_hist: ~10x fewer global atomics, no
// per-edge write-through traffic.
__global__ __launch_bounds__(256) void k_bhist(const int* __restrict__ rows, int* __restrict__ bcount,
                                               int e, int nb) {
  __shared__ int hist[512];
  int t = threadIdx.x;
  for (int i = t; i < nb; i += 256) hist[i] = 0;
  __syncthreads();
  int e0 = blockIdx.x * 4096;
#pragma unroll
  for (int j = 0; j < 16; ++j) {
    int idx = e0 + j * 256 + t;
    if (idx < e) atomicAdd(&hist[rows[idx] >> 8], 1);
  }
  __syncthreads();
  for (int i = t; i < nb; i += 256) {
    int c = hist[i];
    if (c) atomicAdd(&bcount[i], c);
  }
}

// single-block scan of both bucket-count arrays -> bucket starts (nb+1) + cursor copies
__global__ __launch_bounds__(512) void k_bscan(const int* __restrict__ c1, const int* __restrict__ c2,
                                               int* __restrict__ s1, int* __restrict__ s2,
                                               int* __restrict__ bc1, int* __restrict__ bc2, int nb) {
  __shared__ int sh[512];
  int t = threadIdx.x;
  for (int g = 0; g < 2; ++g) {
    const int* c = g ? c2 : c1;
    int* s  = g ? s2 : s1;
    int* bc = g ? bc2 : bc1;
    int v = (t < nb) ? c[t] : 0;
    sh[t] = v;
    __syncthreads();
    for (int off = 1; off < 512; off <<= 1) {
      int x = (t >= off) ? sh[t - off] : 0;
      __syncthreads();
      sh[t] += x;
      __syncthreads();
    }
    int excl = (t > 0) ? sh[t - 1] : 0;
    if (t < nb) { s[t] = excl; bc[t] = excl; }
    if (t == nb - 1) s[nb] = sh[t];
    __syncthreads();
  }
}

// ---------------- phase A: bin edges into 256-row buckets (staged packed words) ----------------
// packed = (row & 255) << 17 | col   (requires n <= 131072)
__global__ __launch_bounds__(256) void k_bin(const int* __restrict__ rows, const int* __restrict__ cols,
                                             int* __restrict__ bcur, unsigned* __restrict__ stg,
                                             int e, int nb) {
  __shared__ int hist[512];
  __shared__ int cur[512];
  int t = threadIdx.x;
  for (int i = t; i < nb; i += 256) hist[i] = 0;
  __syncthreads();
  int e0 = blockIdx.x * 4096;
  int rr[16], cc[16];
#pragma unroll
  for (int j = 0; j < 16; ++j) {
    int idx = e0 + j * 256 + t;
    if (idx < e) {
      rr[j] = rows[idx];
      cc[j] = cols[idx];
      atomicAdd(&hist[rr[j] >> 8], 1);
    } else rr[j] = -1;
  }
  __syncthreads();
  for (int i = t; i < nb; i += 256) {
    int c = hist[i];
    cur[i] = c ? atomicAdd(&bcur[i], c) : 0;
  }
  __syncthreads();
#pragma unroll
  for (int j = 0; j < 16; ++j) {
    if (rr[j] >= 0) {
      int b = rr[j] >> 8;
      int p = atomicAdd(&cur[b], 1);
      stg[p] = ((unsigned)(rr[j] & 255) << 17) | (unsigned)cc[j];
    }
  }
}

// ---------------- phase B: per-bucket degree hist + scan + scatter into final CSR ----------------
// emits rp (row starts), pos (row ends), d = deg^-1/2, and the column CSR.
__global__ __launch_bounds__(256) void k_debin(const unsigned* __restrict__ stg, const int* __restrict__ bstart,
                                               int* __restrict__ rp, int* __restrict__ pos,
                                               float* __restrict__ d, int* __restrict__ csr, int n) {
  __shared__ int hist[256];
  __shared__ int offs[256];
  __shared__ int cur[256];
  int b = blockIdx.x, t = threadIdx.x;
  int start = bstart[b], next = bstart[b + 1];
  hist[t] = 0;
  __syncthreads();
  for (int i = start + t; i < next; i += 256)
    atomicAdd(&hist[stg[i] >> 17], 1);
  __syncthreads();
  int v = hist[t];
  offs[t] = v;
  __syncthreads();
  for (int off = 1; off < 256; off <<= 1) {
    int x = (t >= off) ? offs[t - off] : 0;
    __syncthreads();
    offs[t] += x;
    __syncthreads();
  }
  int excl = start + ((t > 0) ? offs[t - 1] : 0);
  cur[t] = excl;
  int row_g = (b << 8) + t;
  if (row_g < n) {
    rp[row_g]  = excl;
    pos[row_g] = excl + v;
    d[row_g]   = (v > 0) ? 1.0f / sqrtf((float)v) : 0.0f;
  }
  __syncthreads();
  for (int i = start + t; i < next; i += 256) {
    unsigned pk = stg[i];
    int ro = (int)(pk >> 17);
    int col = (int)(pk & 0x1FFFFu);
    int p = atomicAdd(&cur[ro], 1);
    csr[p] = col;
  }
}

// ---------------- fused embed GEMM (bf16 MFMA) + 112-wide projection + d-prescale ----------------
// T layout (contiguous floats): t0[N*16] t1[N*16] t2[N*16] U1[N*32] U2[N*32]
// U1 = [t3|t5] prescaled by d1[row], U2 = [t4|t6] prescaled by d2[row]
__global__ __launch_bounds__(256) void k_embed(const float* __restrict__ x, const float* __restrict__ we,
                                               const float* __restrict__ wcl,
                                               const float* __restrict__ d1, const float* __restrict__ d2,
                                               float* __restrict__ T, int n) {
  __shared__ float pool[7168];          // phase1: xs bf16[64][72] + wsb bf16[64][72]; phase2: wall f32[64][112]
  __shared__ float rs[64 * 68];
  unsigned short* xs  = (unsigned short*)pool;           // A tile, [row][k] bf16, stride 72
  unsigned short* wsb = (unsigned short*)(pool + 2304);  // B tile transposed, [n][k] bf16, stride 72

  const int t    = threadIdx.x;
  const int w    = t >> 6;        // wave 0..3
  const int l    = t & 63;
  const int quad = l >> 4;
  const int lr   = l & 15;
  const int br   = blockIdx.x * 64;

  // x staging: thread t -> row t>>2, 4x float4 at col (t&3)*4 + j*16 (64B contiguous per 4 lanes)
  const int sxr = t >> 2;
  const int sxc = (t & 3) * 4;
  const int xrow = min(br + sxr, n - 1);
  const float* xp = x + (size_t)xrow * NFEAT;
  // we staging (transpose): thread t -> n = t&63, k rows (t>>6)*4 + i + p*16
  const int swn = t & 63;
  const int swk = (t >> 6) * 4;

  f32x4 acc[4];
#pragma unroll
  for (int i = 0; i < 4; ++i) acc[i] = (f32x4){0.f, 0.f, 0.f, 0.f};

  for (int kc = 0; kc < NFEAT; kc += 64) {
    float4 xv[4];
#pragma unroll
    for (int j = 0; j < 4; ++j) xv[j] = *(const float4*)(xp + kc + j * 16 + sxc);
    float wv[16];
#pragma unroll
    for (int p = 0; p < 4; ++p)
#pragma unroll
      for (int i = 0; i < 4; ++i)
        wv[p * 4 + i] = we[(size_t)(kc + p * 16 + swk + i) * HID + swn];
    __syncthreads();   // all waves done reading fragments of previous chunk
#pragma unroll
    for (int j = 0; j < 4; ++j) {
      ushort4 u;
      u.x = f2bf(xv[j].x); u.y = f2bf(xv[j].y); u.z = f2bf(xv[j].z); u.w = f2bf(xv[j].w);
      *(ushort4*)&xs[sxr * 72 + j * 16 + sxc] = u;
    }
#pragma unroll
    for (int p = 0; p < 4; ++p) {
      ushort4 u;
      u.x = f2bf(wv[p * 4 + 0]); u.y = f2bf(wv[p * 4 + 1]);
      u.z = f2bf(wv[p * 4 + 2]); u.w = f2bf(wv[p * 4 + 3]);
      *(ushort4*)&wsb[swn * 72 + p * 16 + swk] = u;
    }
    __syncthreads();
#pragma unroll
    for (int ks = 0; ks < 2; ++ks) {
      bf16x8 af = *(const bf16x8*)&xs[(w * 16 + lr) * 72 + ks * 32 + quad * 8];
#pragma unroll
      for (int nt = 0; nt < 4; ++nt) {
        bf16x8 bfr = *(const bf16x8*)&wsb[(nt * 16 + lr) * 72 + ks * 32 + quad * 8];
        acc[nt] = __builtin_amdgcn_mfma_f32_16x16x32_bf16(af, bfr, acc[nt], 0, 0, 0);
      }
    }
  }
  __syncthreads();

  // relu -> rs; C/D layout: col = lane&15, row = quad*4 + reg
#pragma unroll
  for (int nt = 0; nt < 4; ++nt)
#pragma unroll
    for (int r = 0; r < 4; ++r)
      rs[(w * 16 + quad * 4 + r) * 68 + nt * 16 + lr] = fmaxf(acc[nt][r], 0.f);

  // wall load, permuted block order [t0 t1 t2 t3 t5 t4 t6]
  const int srcblk[7] = {0, 1, 2, 3, 5, 4, 6};
  for (int i = t; i < 7168; i += 256) {
    int k = i / 112, c = i % 112;
    int p = c >> 4, cc = c & 15;
    pool[i] = wcl[(size_t)(64 * srcblk[p] + k) * NC + cc];
  }
  __syncthreads();

  const int prow = t >> 2, pcg = t & 3;
  float4 ap[7];
#pragma unroll
  for (int j = 0; j < 7; ++j) ap[j] = make_float4(0.f, 0.f, 0.f, 0.f);
  for (int k = 0; k < 64; ++k) {
    float rv = rs[prow * 68 + k];
#pragma unroll
    for (int j = 0; j < 7; ++j) {
      float4 w4 = *(const float4*)&pool[k * 112 + pcg * 28 + j * 4];
      ap[j].x += rv * w4.x; ap[j].y += rv * w4.y; ap[j].z += rv * w4.z; ap[j].w += rv * w4.w;
    }
  }
  int gr = br + prow;
  if (gr < n) {
    size_t sn = (size_t)n;
    float d1v = d1[gr], d2v = d2[gr];
#pragma unroll
    for (int j = 0; j < 7; ++j) {
      int c = pcg * 28 + j * 4;
      int p = c >> 4, cc = c & 15;
      float s = (p < 3) ? 1.0f : ((p < 5) ? d1v : d2v);
      float4 v = ap[j];
      v.x *= s; v.y *= s; v.z *= s; v.w *= s;
      size_t o;
      if (p < 3)      o = (size_t)p * 16 * sn + (size_t)gr * 16 + cc;
      else if (p < 5) o = 48 * sn + (size_t)gr * 32 + ((p == 4) ? 16 : 0) + cc;
      else            o = 80 * sn + (size_t)gr * 32 + ((p == 6) ? 16 : 0) + cc;
      *(float4*)(T + o) = v;
    }
  }
}

// ---------------- CSR SpMM (binary A, pre-scaled src): dst = d[row] * sum_{c} src[c] ----------------
template <int L>
__global__ __launch_bounds__(256) void k_spmm(const int* __restrict__ rp, const int* __restrict__ re,
                                              const int* __restrict__ cols, const float* __restrict__ d,
                                              const float* __restrict__ src, float* __restrict__ dst, int n) {
  int t = blockIdx.x * 256 + threadIdx.x;
  int row = t / L;
  if (row >= n) return;
  int sub = t % L;
  int e = rp[row], end = re[row];
  const float4* s4 = (const float4*)src;
  float4 acc = make_float4(0.f, 0.f, 0.f, 0.f);
  for (; e < end; ++e) {
    int c = cols[e];
    float4 g = s4[(size_t)c * L + sub];
    acc.x += g.x; acc.y += g.y; acc.z += g.z; acc.w += g.w;
  }
  float s = d[row];
  acc.x *= s; acc.y *= s; acc.z *= s; acc.w *= s;
  ((float4*)dst)[(size_t)row * L + sub] = acc;
}

// ---------------- combine: p = d1*(t1 + P1.lo + P2.lo) ; q = d2*(t2 + P1.hi + P2.hi) ----------------
__global__ __launch_bounds__(256) void k_combine(float* __restrict__ t1, float* __restrict__ t2,
                                                 const float* __restrict__ P1, const float* __restrict__ P2,
                                                 const float* __restrict__ d1, const float* __restrict__ d2,
                                                 int n) {
  int t = blockIdx.x * 256 + threadIdx.x;
  if (t >= n * 4) return;
  int row = t >> 2, c = t & 3;
  float s1 = d1[row], s2 = d2[row];
  float4* T1 = (float4*)t1;
  float4* T2 = (float4*)t2;
  const float4* p1 = (const float4*)P1;
  const float4* p2 = (const float4*)P2;
  float4 a = T1[t], u = p1[(size_t)row * 8 + c], w = p2[(size_t)row * 8 + c];
  a.x = (a.x + u.x + w.x) * s1; a.y = (a.y + u.y + w.y) * s1;
  a.z = (a.z + u.z + w.z) * s1; a.w = (a.w + u.w + w.w) * s1;
  T1[t] = a;
  float4 b = T2[t];
  u = p1[(size_t)row * 8 + 4 + c]; w = p2[(size_t)row * 8 + 4 + c];
  b.x = (b.x + u.x + w.x) * s2; b.y = (b.y + u.y + w.y) * s2;
  b.z = (b.z + u.z + w.z) * s2; b.w = (b.w + u.w + w.w) * s2;
  T2[t] = b;
}

// ---------------- final: out = log_softmax(t0 + zA + zB) ----------------
__global__ __launch_bounds__(256) void k_final(const float* __restrict__ t0, const float* __restrict__ zA,
                                               const float* __restrict__ zB, float* __restrict__ out, int n) {
  int row = blockIdx.x * 256 + threadIdx.x;
  if (row >= n) return;
  const float4* a4 = (const float4*)t0;
  const float4* b4 = (const float4*)zA;
  const float4* c4 = (const float4*)zB;
  float z[16];
#pragma unroll
  for (int j = 0; j < 4; ++j) {
    float4 a = a4[(size_t)row * 4 + j], b = b4[(size_t)row * 4 + j], c = c4[(size_t)row * 4 + j];
    z[j * 4 + 0] = a.x + b.x + c.x;
    z[j * 4 + 1] = a.y + b.y + c.y;
    z[j * 4 + 2] = a.z + b.z + c.z;
    z[j * 4 + 3] = a.w + b.w + c.w;
  }
  float m = z[0];
#pragma unroll
  for (int i = 1; i < 16; ++i) m = fmaxf(m, z[i]);
  float s = 0.f;
#pragma unroll
  for (int i = 0; i < 16; ++i) s += expf(z[i] - m);
  float lg = m + logf(s);
  float4* o4 = (float4*)out;
#pragma unroll
  for (int j = 0; j < 4; ++j) {
    float4 o;
    o.x = z[j * 4 + 0] - lg; o.y = z[j * 4 + 1] - lg;
    o.z = z[j * 4 + 2] - lg; o.w = z[j * 4 + 3] - lg;
    o4[(size_t)row * 4 + j] = o;
  }
}

extern "C" void kernel_launch(void* const* d_in, const int* in_sizes, int n_in,
                              void* d_out, int out_size, void* d_ws, size_t ws_size,
                              hipStream_t stream) {
  const float* x   = (const float*)d_in[0];
  const int*   a1i = (const int*)d_in[1];
  const int*   a2i = (const int*)d_in[3];
  const float* we  = (const float*)d_in[5];
  const float* wcl = (const float*)d_in[6];
  float* out = (float*)d_out;

  const int n  = in_sizes[0] / NFEAT;
  const int e1 = in_sizes[2];
  const int e2 = in_sizes[4];
  const int nb = (n + 255) / 256;   // <= 512 (requires n <= 131072)

  char* ws = (char*)d_ws;
  size_t off = 0;
  auto alloc = [&](size_t bytes) -> void* {
    void* p = ws + off;
    off += (bytes + 255) & ~(size_t)255;
    return p;
  };
  // T block contiguous: t0,t1,t2,U1,U2
  float* t0 = (float*)alloc((size_t)n * 16 * 4);
  float* t1 = (float*)alloc((size_t)n * 16 * 4);
  float* t2 = (float*)alloc((size_t)n * 16 * 4);
  float* U1 = (float*)alloc((size_t)n * 32 * 4);
  float* U2 = (float*)alloc((size_t)n * 32 * 4);
  float* P1 = (float*)alloc((size_t)n * 32 * 4);
  float* P2 = (float*)alloc((size_t)n * 32 * 4);
  int* rp1  = (int*)alloc((size_t)n * 4);
  int* pos1 = (int*)alloc((size_t)n * 4);
  int* rp2  = (int*)alloc((size_t)n * 4);
  int* pos2 = (int*)alloc((size_t)n * 4);
  float* d1 = (float*)alloc((size_t)n * 4);
  float* d2 = (float*)alloc((size_t)n * 4);
  int*      col1 = (int*)alloc((size_t)e1 * 4);
  int*      col2 = (int*)alloc((size_t)e2 * 4);
  unsigned* stg1 = (unsigned*)alloc((size_t)e1 * 4);
  unsigned* stg2 = (unsigned*)alloc((size_t)e2 * 4);
  int* bcnt1 = (int*)alloc(4096);
  int* bcnt2 = (int*)alloc(4096);
  int* bst1  = (int*)alloc(4096);   // nb+1 entries
  int* bst2  = (int*)alloc(4096);
  int* bc1   = (int*)alloc(4096);
  int* bc2   = (int*)alloc(4096);
  float* zA = U1;  // U1/U2 dead after inner spmm passes
  float* zB = U2;

  (void)ws_size; (void)n_in; (void)out_size;

  hipMemsetAsync(bcnt1, 0, (size_t)nb * 4, stream);
  hipMemsetAsync(bcnt2, 0, (size_t)nb * 4, stream);

  // bucket-level histograms (LDS-staged; replaces per-row global-atomic k_hist)
  k_bhist<<<(e1 + 4095) / 4096, 256, 0, stream>>>(a1i, bcnt1, e1, nb);
  k_bhist<<<(e2 + 4095) / 4096, 256, 0, stream>>>(a2i, bcnt2, e2, nb);

  // scan bucket counts -> bucket starts + phase-A cursors
  k_bscan<<<1, 512, 0, stream>>>(bcnt1, bcnt2, bst1, bst2, bc1, bc2, nb);

  // phase A: bin by row>>8 into staged packed words
  k_bin<<<(e1 + 4095) / 4096, 256, 0, stream>>>(a1i, a1i + e1, bc1, stg1, e1, nb);
  k_bin<<<(e2 + 4095) / 4096, 256, 0, stream>>>(a2i, a2i + e2, bc2, stg2, e2, nb);

  // phase B: per-bucket degree hist + scan + L2-local scatter into CSR
  // emits rp (starts), pos (ends), d = deg^-1/2
  k_debin<<<nb, 256, 0, stream>>>(stg1, bst1, rp1, pos1, d1, col1, n);
  k_debin<<<nb, 256, 0, stream>>>(stg2, bst2, rp2, pos2, d2, col2, n);

  k_embed<<<(n + 63) / 64, 256, 0, stream>>>(x, we, wcl, d1, d2, t0, n);

  // inner passes (width 32): P1 = d1*(A1 @ U1), P2 = d2*(A2 @ U2)
  k_spmm<8><<<(n * 8 + 255) / 256, 256, 0, stream>>>(rp1, pos1, col1, d1, U1, P1, n);
  k_spmm<8><<<(n * 8 + 255) / 256, 256, 0, stream>>>(rp2, pos2, col2, d2, U2, P2, n);

  // combine into outer-pass sources (pre-scaled)
  k_combine<<<(n * 4 + 255) / 256, 256, 0, stream>>>(t1, t2, P1, P2, d1, d2, n);

  // outer passes (width 16): zA = d1*(A1 @ p), zB = d2*(A2 @ q)
  k_spmm<4><<<(n * 4 + 255) / 256, 256, 0, stream>>>(rp1, pos1, col1, d1, t1, zA, n);
  k_spmm<4><<<(n * 4 + 255) / 256, 256, 0, stream>>>(rp2, pos2, col2, d2, t2, zB, n);

  k_final<<<(n + 255) / 256, 256, 0, stream>>>(t0, zA, zB, out, n);
}

// Round 2
// 1186.717 us; speedup vs baseline: 1.3552x; 1.0970x over previous
//
#include <hip/hip_runtime.h>

constexpr int NFEAT = 1024;
constexpr int HID   = 64;
constexpr int NC    = 16;

typedef __attribute__((ext_vector_type(8))) short bf16x8;
typedef __attribute__((ext_vector_type(4))) float f32x4;
typedef __attribute__((ext_vector_type(8))) unsigned short u16x8;

__device__ inline unsigned short f2bf(float f) {
  unsigned u = __float_as_uint(f);
  unsigned r = u + 0x7FFFu + ((u >> 16) & 1u);
  return (unsigned short)(r >> 16);
}
__device__ inline float bflo(unsigned u) { return __uint_as_float(u << 16); }
__device__ inline float bfhi(unsigned u) { return __uint_as_float(u & 0xFFFF0000u); }

// ---------------- bucket-level histogram (row>>8), LDS-staged ----------------
__global__ __launch_bounds__(256) void k_bhist(const int* __restrict__ rows, int* __restrict__ bcount,
                                               int e, int nb) {
  __shared__ int hist[512];
  int t = threadIdx.x;
  for (int i = t; i < nb; i += 256) hist[i] = 0;
  __syncthreads();
  int e0 = blockIdx.x * 4096;
#pragma unroll
  for (int j = 0; j < 16; ++j) {
    int idx = e0 + j * 256 + t;
    if (idx < e) atomicAdd(&hist[rows[idx] >> 8], 1);
  }
  __syncthreads();
  for (int i = t; i < nb; i += 256) {
    int c = hist[i];
    if (c) atomicAdd(&bcount[i], c);
  }
}

// single-block scan of both bucket-count arrays -> bucket starts (nb+1) + cursor copies
__global__ __launch_bounds__(512) void k_bscan(const int* __restrict__ c1, const int* __restrict__ c2,
                                               int* __restrict__ s1, int* __restrict__ s2,
                                               int* __restrict__ bc1, int* __restrict__ bc2, int nb) {
  __shared__ int sh[512];
  int t = threadIdx.x;
  for (int g = 0; g < 2; ++g) {
    const int* c = g ? c2 : c1;
    int* s  = g ? s2 : s1;
    int* bc = g ? bc2 : bc1;
    int v = (t < nb) ? c[t] : 0;
    sh[t] = v;
    __syncthreads();
    for (int off = 1; off < 512; off <<= 1) {
      int x = (t >= off) ? sh[t - off] : 0;
      __syncthreads();
      sh[t] += x;
      __syncthreads();
    }
    int excl = (t > 0) ? sh[t - 1] : 0;
    if (t < nb) { s[t] = excl; bc[t] = excl; }
    if (t == nb - 1) s[nb] = sh[t];
    __syncthreads();
  }
}

// ---------------- phase A: bin edges into 256-row buckets (staged packed words) ----------------
// packed = (row & 255) << 17 | col   (requires n <= 131072)
__global__ __launch_bounds__(256) void k_bin(const int* __restrict__ rows, const int* __restrict__ cols,
                                             int* __restrict__ bcur, unsigned* __restrict__ stg,
                                             int e, int nb) {
  __shared__ int hist[512];
  __shared__ int cur[512];
  int t = threadIdx.x;
  for (int i = t; i < nb; i += 256) hist[i] = 0;
  __syncthreads();
  int e0 = blockIdx.x * 4096;
  int rr[16], cc[16];
#pragma unroll
  for (int j = 0; j < 16; ++j) {
    int idx = e0 + j * 256 + t;
    if (idx < e) {
      rr[j] = rows[idx];
      cc[j] = cols[idx];
      atomicAdd(&hist[rr[j] >> 8], 1);
    } else rr[j] = -1;
  }
  __syncthreads();
  for (int i = t; i < nb; i += 256) {
    int c = hist[i];
    cur[i] = c ? atomicAdd(&bcur[i], c) : 0;
  }
  __syncthreads();
#pragma unroll
  for (int j = 0; j < 16; ++j) {
    if (rr[j] >= 0) {
      int b = rr[j] >> 8;
      int p = atomicAdd(&cur[b], 1);
      stg[p] = ((unsigned)(rr[j] & 255) << 17) | (unsigned)cc[j];
    }
  }
}

// ---------------- phase B: per-bucket degree hist + scan + scatter into final CSR ----------------
__global__ __launch_bounds__(256) void k_debin(const unsigned* __restrict__ stg, const int* __restrict__ bstart,
                                               int* __restrict__ rp, int* __restrict__ pos,
                                               float* __restrict__ d, int* __restrict__ csr, int n) {
  __shared__ int hist[256];
  __shared__ int offs[256];
  __shared__ int cur[256];
  int b = blockIdx.x, t = threadIdx.x;
  int start = bstart[b], next = bstart[b + 1];
  hist[t] = 0;
  __syncthreads();
  for (int i = start + t; i < next; i += 256)
    atomicAdd(&hist[stg[i] >> 17], 1);
  __syncthreads();
  int v = hist[t];
  offs[t] = v;
  __syncthreads();
  for (int off = 1; off < 256; off <<= 1) {
    int x = (t >= off) ? offs[t - off] : 0;
    __syncthreads();
    offs[t] += x;
    __syncthreads();
  }
  int excl = start + ((t > 0) ? offs[t - 1] : 0);
  cur[t] = excl;
  int row_g = (b << 8) + t;
  if (row_g < n) {
    rp[row_g]  = excl;
    pos[row_g] = excl + v;
    d[row_g]   = (v > 0) ? 1.0f / sqrtf((float)v) : 0.0f;
  }
  __syncthreads();
  for (int i = start + t; i < next; i += 256) {
    unsigned pk = stg[i];
    int ro = (int)(pk >> 17);
    int col = (int)(pk & 0x1FFFFu);
    int p = atomicAdd(&cur[ro], 1);
    csr[p] = col;
  }
}

// ---------------- fused embed GEMM (bf16 MFMA) + 112-wide projection + d-prescale ----------------
// T: t0,t1,t2 f32 [n*16] each (contiguous). U1,U2: bf16 [n*32], prescaled by d1/d2.
__global__ __launch_bounds__(256) void k_embed(const float* __restrict__ x, const float* __restrict__ we,
                                               const float* __restrict__ wcl,
                                               const float* __restrict__ d1, const float* __restrict__ d2,
                                               float* __restrict__ T,
                                               unsigned short* __restrict__ U1, unsigned short* __restrict__ U2,
                                               int n) {
  __shared__ float pool[7168];          // phase1: xs bf16[64][72] + wsb bf16[64][72]; phase2: wall f32[64][112]
  __shared__ float rs[64 * 68];
  unsigned short* xs  = (unsigned short*)pool;           // A tile, [row][k] bf16, stride 72
  unsigned short* wsb = (unsigned short*)(pool + 2304);  // B tile transposed, [n][k] bf16, stride 72

  const int t    = threadIdx.x;
  const int w    = t >> 6;        // wave 0..3
  const int l    = t & 63;
  const int quad = l >> 4;
  const int lr   = l & 15;
  const int br   = blockIdx.x * 64;

  const int sxr = t >> 2;
  const int sxc = (t & 3) * 4;
  const int xrow = min(br + sxr, n - 1);
  const float* xp = x + (size_t)xrow * NFEAT;
  const int swn = t & 63;
  const int swk = (t >> 6) * 4;

  f32x4 acc[4];
#pragma unroll
  for (int i = 0; i < 4; ++i) acc[i] = (f32x4){0.f, 0.f, 0.f, 0.f};

  for (int kc = 0; kc < NFEAT; kc += 64) {
    float4 xv[4];
#pragma unroll
    for (int j = 0; j < 4; ++j) xv[j] = *(const float4*)(xp + kc + j * 16 + sxc);
    float wv[16];
#pragma unroll
    for (int p = 0; p < 4; ++p)
#pragma unroll
      for (int i = 0; i < 4; ++i)
        wv[p * 4 + i] = we[(size_t)(kc + p * 16 + swk + i) * HID + swn];
    __syncthreads();
#pragma unroll
    for (int j = 0; j < 4; ++j) {
      ushort4 u;
      u.x = f2bf(xv[j].x); u.y = f2bf(xv[j].y); u.z = f2bf(xv[j].z); u.w = f2bf(xv[j].w);
      *(ushort4*)&xs[sxr * 72 + j * 16 + sxc] = u;
    }
#pragma unroll
    for (int p = 0; p < 4; ++p) {
      ushort4 u;
      u.x = f2bf(wv[p * 4 + 0]); u.y = f2bf(wv[p * 4 + 1]);
      u.z = f2bf(wv[p * 4 + 2]); u.w = f2bf(wv[p * 4 + 3]);
      *(ushort4*)&wsb[swn * 72 + p * 16 + swk] = u;
    }
    __syncthreads();
#pragma unroll
    for (int ks = 0; ks < 2; ++ks) {
      bf16x8 af = *(const bf16x8*)&xs[(w * 16 + lr) * 72 + ks * 32 + quad * 8];
#pragma unroll
      for (int nt = 0; nt < 4; ++nt) {
        bf16x8 bfr = *(const bf16x8*)&wsb[(nt * 16 + lr) * 72 + ks * 32 + quad * 8];
        acc[nt] = __builtin_amdgcn_mfma_f32_16x16x32_bf16(af, bfr, acc[nt], 0, 0, 0);
      }
    }
  }
  __syncthreads();

#pragma unroll
  for (int nt = 0; nt < 4; ++nt)
#pragma unroll
    for (int r = 0; r < 4; ++r)
      rs[(w * 16 + quad * 4 + r) * 68 + nt * 16 + lr] = fmaxf(acc[nt][r], 0.f);

  // wall load, permuted block order [t0 t1 t2 t3 t5 t4 t6]
  const int srcblk[7] = {0, 1, 2, 3, 5, 4, 6};
  for (int i = t; i < 7168; i += 256) {
    int k = i / 112, c = i % 112;
    int p = c >> 4, cc = c & 15;
    pool[i] = wcl[(size_t)(64 * srcblk[p] + k) * NC + cc];
  }
  __syncthreads();

  const int prow = t >> 2, pcg = t & 3;
  float4 ap[7];
#pragma unroll
  for (int j = 0; j < 7; ++j) ap[j] = make_float4(0.f, 0.f, 0.f, 0.f);
  for (int k = 0; k < 64; ++k) {
    float rv = rs[prow * 68 + k];
#pragma unroll
    for (int j = 0; j < 7; ++j) {
      float4 w4 = *(const float4*)&pool[k * 112 + pcg * 28 + j * 4];
      ap[j].x += rv * w4.x; ap[j].y += rv * w4.y; ap[j].z += rv * w4.z; ap[j].w += rv * w4.w;
    }
  }
  int gr = br + prow;
  if (gr < n) {
    size_t sn = (size_t)n;
    float d1v = d1[gr], d2v = d2[gr];
#pragma unroll
    for (int j = 0; j < 7; ++j) {
      int c = pcg * 28 + j * 4;
      int pb = c >> 4, cc = c & 15;
      float4 v = ap[j];
      if (pb < 3) {
        size_t o = (size_t)pb * 16 * sn + (size_t)gr * 16 + cc;
        *(float4*)(T + o) = v;
      } else {
        float s = (pb < 5) ? d1v : d2v;
        v.x *= s; v.y *= s; v.z *= s; v.w *= s;
        ushort4 u;
        u.x = f2bf(v.x); u.y = f2bf(v.y); u.z = f2bf(v.z); u.w = f2bf(v.w);
        unsigned short* Ub = (pb < 5) ? U1 : U2;
        int half = (pb == 4 || pb == 6) ? 16 : 0;
        *(ushort4*)(Ub + (size_t)gr * 32 + half + cc) = u;
      }
    }
  }
}

// ---------------- fused inner passes + combine ----------------
// per row: a1 = sum_{A1} U1[c] (32w bf16), a2 = sum_{A2} U2[c]
// p = d1*(t1 + d1*a1.lo + d2*a2.lo)  (bf16, 16w)
// q = d2*(t2 + d1*a1.hi + d2*a2.hi)  (bf16, 16w)
__global__ __launch_bounds__(256) void k_inner(const int* __restrict__ rp1, const int* __restrict__ pe1,
                                               const int* __restrict__ col1,
                                               const int* __restrict__ rp2, const int* __restrict__ pe2,
                                               const int* __restrict__ col2,
                                               const float* __restrict__ d1, const float* __restrict__ d2,
                                               const unsigned short* __restrict__ U1,
                                               const unsigned short* __restrict__ U2,
                                               const float* __restrict__ t1, const float* __restrict__ t2,
                                               unsigned short* __restrict__ p, unsigned short* __restrict__ q,
                                               int n) {
  int t = blockIdx.x * 256 + threadIdx.x;
  int row = t >> 2;
  if (row >= n) return;
  int sub = t & 3;           // 8-element slice of the 32-wide row
  float a1[8] = {0, 0, 0, 0, 0, 0, 0, 0};
  float a2[8] = {0, 0, 0, 0, 0, 0, 0, 0};
  for (int e = rp1[row], end = pe1[row]; e < end; ++e) {
    int c = col1[e];
    uint4 v = *(const uint4*)(U1 + (size_t)c * 32 + sub * 8);
    a1[0] += bflo(v.x); a1[1] += bfhi(v.x);
    a1[2] += bflo(v.y); a1[3] += bfhi(v.y);
    a1[4] += bflo(v.z); a1[5] += bfhi(v.z);
    a1[6] += bflo(v.w); a1[7] += bfhi(v.w);
  }
  for (int e = rp2[row], end = pe2[row]; e < end; ++e) {
    int c = col2[e];
    uint4 v = *(const uint4*)(U2 + (size_t)c * 32 + sub * 8);
    a2[0] += bflo(v.x); a2[1] += bfhi(v.x);
    a2[2] += bflo(v.y); a2[3] += bfhi(v.y);
    a2[4] += bflo(v.z); a2[5] += bfhi(v.z);
    a2[6] += bflo(v.w); a2[7] += bfhi(v.w);
  }
  float s1 = d1[row], s2 = d2[row];
  const float* tb = (sub < 2) ? (t1 + (size_t)row * 16 + sub * 8)
                              : (t2 + (size_t)row * 16 + (sub - 2) * 8);
  unsigned short* dst = (sub < 2) ? (p + (size_t)row * 16 + sub * 8)
                                  : (q + (size_t)row * 16 + (sub - 2) * 8);
  float so = (sub < 2) ? s1 : s2;
  float4 b0 = *(const float4*)tb;
  float4 b1 = *(const float4*)(tb + 4);
  float bb[8] = {b0.x, b0.y, b0.z, b0.w, b1.x, b1.y, b1.z, b1.w};
  u16x8 us;
#pragma unroll
  for (int i = 0; i < 8; ++i) {
    float v = so * (bb[i] + s1 * a1[i] + s2 * a2[i]);
    us[i] = f2bf(v);
  }
  *(u16x8*)dst = us;
}

// ---------------- fused outer passes + log_softmax ----------------
// z = t0 + d1*sum_{A1} p[c] + d2*sum_{A2} q[c]; out = log_softmax(z)
__global__ __launch_bounds__(256) void k_outer(const int* __restrict__ rp1, const int* __restrict__ pe1,
                                               const int* __restrict__ col1,
                                               const int* __restrict__ rp2, const int* __restrict__ pe2,
                                               const int* __restrict__ col2,
                                               const float* __restrict__ d1, const float* __restrict__ d2,
                                               const unsigned short* __restrict__ p,
                                               const unsigned short* __restrict__ q,
                                               const float* __restrict__ t0, float* __restrict__ out,
                                               int n) {
  int t = blockIdx.x * 256 + threadIdx.x;
  int row = t >> 2;
  if (row >= n) return;
  int sub = t & 3;           // 4-element slice of the 16-wide logits
  float a[4] = {0, 0, 0, 0}, b[4] = {0, 0, 0, 0};
  for (int e = rp1[row], end = pe1[row]; e < end; ++e) {
    int c = col1[e];
    uint2 v = *(const uint2*)(p + (size_t)c * 16 + sub * 4);
    a[0] += bflo(v.x); a[1] += bfhi(v.x);
    a[2] += bflo(v.y); a[3] += bfhi(v.y);
  }
  for (int e = rp2[row], end = pe2[row]; e < end; ++e) {
    int c = col2[e];
    uint2 v = *(const uint2*)(q + (size_t)c * 16 + sub * 4);
    b[0] += bflo(v.x); b[1] += bfhi(v.x);
    b[2] += bflo(v.y); b[3] += bfhi(v.y);
  }
  float s1 = d1[row], s2 = d2[row];
  float4 t0v = *(const float4*)(t0 + (size_t)row * 16 + sub * 4);
  float z[4];
  z[0] = t0v.x + s1 * a[0] + s2 * b[0];
  z[1] = t0v.y + s1 * a[1] + s2 * b[1];
  z[2] = t0v.z + s1 * a[2] + s2 * b[2];
  z[3] = t0v.w + s1 * a[3] + s2 * b[3];
  float m = fmaxf(fmaxf(z[0], z[1]), fmaxf(z[2], z[3]));
  m = fmaxf(m, __shfl_xor(m, 1));
  m = fmaxf(m, __shfl_xor(m, 2));
  float s = expf(z[0] - m) + expf(z[1] - m) + expf(z[2] - m) + expf(z[3] - m);
  s += __shfl_xor(s, 1);
  s += __shfl_xor(s, 2);
  float lg = m + logf(s);
  float4 o;
  o.x = z[0] - lg; o.y = z[1] - lg; o.z = z[2] - lg; o.w = z[3] - lg;
  *(float4*)(out + (size_t)row * 16 + sub * 4) = o;
}

extern "C" void kernel_launch(void* const* d_in, const int* in_sizes, int n_in,
                              void* d_out, int out_size, void* d_ws, size_t ws_size,
                              hipStream_t stream) {
  const float* x   = (const float*)d_in[0];
  const int*   a1i = (const int*)d_in[1];
  const int*   a2i = (const int*)d_in[3];
  const float* we  = (const float*)d_in[5];
  const float* wcl = (const float*)d_in[6];
  float* out = (float*)d_out;

  const int n  = in_sizes[0] / NFEAT;
  const int e1 = in_sizes[2];
  const int e2 = in_sizes[4];
  const int nb = (n + 255) / 256;   // <= 512 (requires n <= 131072)

  char* ws = (char*)d_ws;
  size_t off = 0;
  auto alloc = [&](size_t bytes) -> void* {
    void* p = ws + off;
    off += (bytes + 255) & ~(size_t)255;
    return p;
  };
  float* t0 = (float*)alloc((size_t)n * 16 * 4);
  float* t1 = (float*)alloc((size_t)n * 16 * 4);
  float* t2 = (float*)alloc((size_t)n * 16 * 4);
  unsigned short* U1 = (unsigned short*)alloc((size_t)n * 32 * 2);   // bf16
  unsigned short* U2 = (unsigned short*)alloc((size_t)n * 32 * 2);   // bf16
  unsigned short* pp = (unsigned short*)alloc((size_t)n * 16 * 2);   // bf16
  unsigned short* qq = (unsigned short*)alloc((size_t)n * 16 * 2);   // bf16
  int* rp1  = (int*)alloc((size_t)n * 4);
  int* pos1 = (int*)alloc((size_t)n * 4);
  int* rp2  = (int*)alloc((size_t)n * 4);
  int* pos2 = (int*)alloc((size_t)n * 4);
  float* d1 = (float*)alloc((size_t)n * 4);
  float* d2 = (float*)alloc((size_t)n * 4);
  int*      col1 = (int*)alloc((size_t)e1 * 4);
  int*      col2 = (int*)alloc((size_t)e2 * 4);
  unsigned* stg1 = (unsigned*)alloc((size_t)e1 * 4);
  unsigned* stg2 = (unsigned*)alloc((size_t)e2 * 4);
  int* bcnt1 = (int*)alloc(4096);
  int* bcnt2 = (int*)alloc(4096);
  int* bst1  = (int*)alloc(4096);   // nb+1 entries
  int* bst2  = (int*)alloc(4096);
  int* bc1   = (int*)alloc(4096);
  int* bc2   = (int*)alloc(4096);

  (void)ws_size; (void)n_in; (void)out_size;

  hipMemsetAsync(bcnt1, 0, (size_t)nb * 4, stream);
  hipMemsetAsync(bcnt2, 0, (size_t)nb * 4, stream);

  k_bhist<<<(e1 + 4095) / 4096, 256, 0, stream>>>(a1i, bcnt1, e1, nb);
  k_bhist<<<(e2 + 4095) / 4096, 256, 0, stream>>>(a2i, bcnt2, e2, nb);

  k_bscan<<<1, 512, 0, stream>>>(bcnt1, bcnt2, bst1, bst2, bc1, bc2, nb);

  k_bin<<<(e1 + 4095) / 4096, 256, 0, stream>>>(a1i, a1i + e1, bc1, stg1, e1, nb);
  k_bin<<<(e2 + 4095) / 4096, 256, 0, stream>>>(a2i, a2i + e2, bc2, stg2, e2, nb);

  k_debin<<<nb, 256, 0, stream>>>(stg1, bst1, rp1, pos1, d1, col1, n);
  k_debin<<<nb, 256, 0, stream>>>(stg2, bst2, rp2, pos2, d2, col2, n);

  k_embed<<<(n + 63) / 64, 256, 0, stream>>>(x, we, wcl, d1, d2, t0, U1, U2, n);

  k_inner<<<(n * 4 + 255) / 256, 256, 0, stream>>>(rp1, pos1, col1, rp2, pos2, col2,
                                                   d1, d2, U1, U2, t1, t2, pp, qq, n);

  k_outer<<<(n * 4 + 255) / 256, 256, 0, stream>>>(rp1, pos1, col1, rp2, pos2, col2,
                                                   d1, d2, pp, qq, t0, out, n);
}

// Round 3
// 1111.865 us; speedup vs baseline: 1.4465x; 1.0673x over previous
//
#include <hip/hip_runtime.h>

constexpr int NFEAT = 1024;
constexpr int HID   = 64;
constexpr int NC    = 16;

typedef __attribute__((ext_vector_type(8))) short bf16x8;
typedef __attribute__((ext_vector_type(4))) float f32x4;
typedef __attribute__((ext_vector_type(8))) unsigned short u16x8;

__device__ inline unsigned short f2bf(float f) {
  unsigned u = __float_as_uint(f);
  unsigned r = u + 0x7FFFu + ((u >> 16) & 1u);
  return (unsigned short)(r >> 16);
}
__device__ inline float bflo(unsigned u) { return __uint_as_float(u << 16); }
__device__ inline float bfhi(unsigned u) { return __uint_as_float(u & 0xFFFF0000u); }

// ---------------- bucket-level histogram (row>>8), LDS-staged ----------------
__global__ __launch_bounds__(256) void k_bhist(const int* __restrict__ rows, int* __restrict__ bcount,
                                               int e, int nb) {
  __shared__ int hist[512];
  int t = threadIdx.x;
  for (int i = t; i < nb; i += 256) hist[i] = 0;
  __syncthreads();
  int e0 = blockIdx.x * 4096;
#pragma unroll
  for (int j = 0; j < 16; ++j) {
    int idx = e0 + j * 256 + t;
    if (idx < e) atomicAdd(&hist[rows[idx] >> 8], 1);
  }
  __syncthreads();
  for (int i = t; i < nb; i += 256) {
    int c = hist[i];
    if (c) atomicAdd(&bcount[i], c);
  }
}

// single-block scan of both bucket-count arrays -> bucket starts (nb+1) + cursor copies
__global__ __launch_bounds__(512) void k_bscan(const int* __restrict__ c1, const int* __restrict__ c2,
                                               int* __restrict__ s1, int* __restrict__ s2,
                                               int* __restrict__ bc1, int* __restrict__ bc2, int nb) {
  __shared__ int sh[512];
  int t = threadIdx.x;
  for (int g = 0; g < 2; ++g) {
    const int* c = g ? c2 : c1;
    int* s  = g ? s2 : s1;
    int* bc = g ? bc2 : bc1;
    int v = (t < nb) ? c[t] : 0;
    sh[t] = v;
    __syncthreads();
    for (int off = 1; off < 512; off <<= 1) {
      int x = (t >= off) ? sh[t - off] : 0;
      __syncthreads();
      sh[t] += x;
      __syncthreads();
    }
    int excl = (t > 0) ? sh[t - 1] : 0;
    if (t < nb) { s[t] = excl; bc[t] = excl; }
    if (t == nb - 1) s[nb] = sh[t];
    __syncthreads();
  }
}

// ---------------- phase A: bin edges into 256-row buckets (staged packed words) ----------------
// packed = (row & 255) << 17 | col   (requires n <= 131072)
__global__ __launch_bounds__(256) void k_bin(const int* __restrict__ rows, const int* __restrict__ cols,
                                             int* __restrict__ bcur, unsigned* __restrict__ stg,
                                             int e, int nb) {
  __shared__ int hist[512];
  __shared__ int cur[512];
  int t = threadIdx.x;
  for (int i = t; i < nb; i += 256) hist[i] = 0;
  __syncthreads();
  int e0 = blockIdx.x * 4096;
  int rr[16], cc[16];
#pragma unroll
  for (int j = 0; j < 16; ++j) {
    int idx = e0 + j * 256 + t;
    if (idx < e) {
      rr[j] = rows[idx];
      cc[j] = cols[idx];
      atomicAdd(&hist[rr[j] >> 8], 1);
    } else rr[j] = -1;
  }
  __syncthreads();
  for (int i = t; i < nb; i += 256) {
    int c = hist[i];
    cur[i] = c ? atomicAdd(&bcur[i], c) : 0;
  }
  __syncthreads();
#pragma unroll
  for (int j = 0; j < 16; ++j) {
    if (rr[j] >= 0) {
      int b = rr[j] >> 8;
      int p = atomicAdd(&cur[b], 1);
      stg[p] = ((unsigned)(rr[j] & 255) << 17) | (unsigned)cc[j];
    }
  }
}

// ---------------- phase B: per-bucket degree hist + scan + scatter into final CSR ----------------
__global__ __launch_bounds__(256) void k_debin(const unsigned* __restrict__ stg, const int* __restrict__ bstart,
                                               int* __restrict__ rp, int* __restrict__ pos,
                                               float* __restrict__ d, int* __restrict__ csr, int n) {
  __shared__ int hist[256];
  __shared__ int offs[256];
  __shared__ int cur[256];
  int b = blockIdx.x, t = threadIdx.x;
  int start = bstart[b], next = bstart[b + 1];
  hist[t] = 0;
  __syncthreads();
  for (int i = start + t; i < next; i += 256)
    atomicAdd(&hist[stg[i] >> 17], 1);
  __syncthreads();
  int v = hist[t];
  offs[t] = v;
  __syncthreads();
  for (int off = 1; off < 256; off <<= 1) {
    int x = (t >= off) ? offs[t - off] : 0;
    __syncthreads();
    offs[t] += x;
    __syncthreads();
  }
  int excl = start + ((t > 0) ? offs[t - 1] : 0);
  cur[t] = excl;
  int row_g = (b << 8) + t;
  if (row_g < n) {
    rp[row_g]  = excl;
    pos[row_g] = excl + v;
    d[row_g]   = (v > 0) ? 1.0f / sqrtf((float)v) : 0.0f;
  }
  __syncthreads();
  for (int i = start + t; i < next; i += 256) {
    unsigned pk = stg[i];
    int ro = (int)(pk >> 17);
    int col = (int)(pk & 0x1FFFFu);
    int p = atomicAdd(&cur[ro], 1);
    csr[p] = col;
  }
}

// ---------------- fused embed GEMM (bf16 MFMA) + 112-wide projection + d-prescale ----------------
// T: t0,t1,t2 f32 [n*16] each (contiguous). U1,U2: bf16 [n*32], prescaled by d1/d2.
__global__ __launch_bounds__(256) void k_embed(const float* __restrict__ x, const float* __restrict__ we,
                                               const float* __restrict__ wcl,
                                               const float* __restrict__ d1, const float* __restrict__ d2,
                                               float* __restrict__ T,
                                               unsigned short* __restrict__ U1, unsigned short* __restrict__ U2,
                                               int n) {
  __shared__ float pool[7168];          // phase1: xs bf16[64][72] + wsb bf16[64][72]; phase2: wall f32[64][112]
  __shared__ float rs[64 * 68];
  unsigned short* xs  = (unsigned short*)pool;           // A tile, [row][k] bf16, stride 72
  unsigned short* wsb = (unsigned short*)(pool + 2304);  // B tile transposed, [n][k] bf16, stride 72

  const int t    = threadIdx.x;
  const int w    = t >> 6;        // wave 0..3
  const int l    = t & 63;
  const int quad = l >> 4;
  const int lr   = l & 15;
  const int br   = blockIdx.x * 64;

  const int sxr = t >> 2;
  const int sxc = (t & 3) * 4;
  const int xrow = min(br + sxr, n - 1);
  const float* xp = x + (size_t)xrow * NFEAT;
  const int swn = t & 63;
  const int swk = (t >> 6) * 4;

  f32x4 acc[4];
#pragma unroll
  for (int i = 0; i < 4; ++i) acc[i] = (f32x4){0.f, 0.f, 0.f, 0.f};

  for (int kc = 0; kc < NFEAT; kc += 64) {
    float4 xv[4];
#pragma unroll
    for (int j = 0; j < 4; ++j) xv[j] = *(const float4*)(xp + kc + j * 16 + sxc);
    float wv[16];
#pragma unroll
    for (int p = 0; p < 4; ++p)
#pragma unroll
      for (int i = 0; i < 4; ++i)
        wv[p * 4 + i] = we[(size_t)(kc + p * 16 + swk + i) * HID + swn];
    __syncthreads();
#pragma unroll
    for (int j = 0; j < 4; ++j) {
      ushort4 u;
      u.x = f2bf(xv[j].x); u.y = f2bf(xv[j].y); u.z = f2bf(xv[j].z); u.w = f2bf(xv[j].w);
      *(ushort4*)&xs[sxr * 72 + j * 16 + sxc] = u;
    }
#pragma unroll
    for (int p = 0; p < 4; ++p) {
      ushort4 u;
      u.x = f2bf(wv[p * 4 + 0]); u.y = f2bf(wv[p * 4 + 1]);
      u.z = f2bf(wv[p * 4 + 2]); u.w = f2bf(wv[p * 4 + 3]);
      *(ushort4*)&wsb[swn * 72 + p * 16 + swk] = u;
    }
    __syncthreads();
#pragma unroll
    for (int ks = 0; ks < 2; ++ks) {
      bf16x8 af = *(const bf16x8*)&xs[(w * 16 + lr) * 72 + ks * 32 + quad * 8];
#pragma unroll
      for (int nt = 0; nt < 4; ++nt) {
        bf16x8 bfr = *(const bf16x8*)&wsb[(nt * 16 + lr) * 72 + ks * 32 + quad * 8];
        acc[nt] = __builtin_amdgcn_mfma_f32_16x16x32_bf16(af, bfr, acc[nt], 0, 0, 0);
      }
    }
  }
  __syncthreads();

#pragma unroll
  for (int nt = 0; nt < 4; ++nt)
#pragma unroll
    for (int r = 0; r < 4; ++r)
      rs[(w * 16 + quad * 4 + r) * 68 + nt * 16 + lr] = fmaxf(acc[nt][r], 0.f);

  // wall load, permuted block order [t0 t1 t2 t3 t5 t4 t6]
  const int srcblk[7] = {0, 1, 2, 3, 5, 4, 6};
  for (int i = t; i < 7168; i += 256) {
    int k = i / 112, c = i % 112;
    int p = c >> 4, cc = c & 15;
    pool[i] = wcl[(size_t)(64 * srcblk[p] + k) * NC + cc];
  }
  __syncthreads();

  const int prow = t >> 2, pcg = t & 3;
  float4 ap[7];
#pragma unroll
  for (int j = 0; j < 7; ++j) ap[j] = make_float4(0.f, 0.f, 0.f, 0.f);
  for (int k = 0; k < 64; ++k) {
    float rv = rs[prow * 68 + k];
#pragma unroll
    for (int j = 0; j < 7; ++j) {
      float4 w4 = *(const float4*)&pool[k * 112 + pcg * 28 + j * 4];
      ap[j].x += rv * w4.x; ap[j].y += rv * w4.y; ap[j].z += rv * w4.z; ap[j].w += rv * w4.w;
    }
  }
  int gr = br + prow;
  if (gr < n) {
    size_t sn = (size_t)n;
    float d1v = d1[gr], d2v = d2[gr];
#pragma unroll
    for (int j = 0; j < 7; ++j) {
      int c = pcg * 28 + j * 4;
      int pb = c >> 4, cc = c & 15;
      float4 v = ap[j];
      if (pb < 3) {
        size_t o = (size_t)pb * 16 * sn + (size_t)gr * 16 + cc;
        *(float4*)(T + o) = v;
      } else {
        float s = (pb < 5) ? d1v : d2v;
        v.x *= s; v.y *= s; v.z *= s; v.w *= s;
        ushort4 u;
        u.x = f2bf(v.x); u.y = f2bf(v.y); u.z = f2bf(v.z); u.w = f2bf(v.w);
        unsigned short* Ub = (pb < 5) ? U1 : U2;
        int half = (pb == 4 || pb == 6) ? 16 : 0;
        *(ushort4*)(Ub + (size_t)gr * 32 + half + cc) = u;
      }
    }
  }
}

// ---------------- fused inner passes + combine (8-deep MLP pipeline) ----------------
// per row: a1 = sum_{A1} U1[c] (32w bf16), a2 = sum_{A2} U2[c]
// p = d1*(t1 + a1.lo + a2.lo)  (bf16, 16w)   [U pre-scaled by d at source]
// q = d2*(t2 + a1.hi + a2.hi)  (bf16, 16w)
__global__ __launch_bounds__(256) void k_inner(const int* __restrict__ rp1, const int* __restrict__ pe1,
                                               const int* __restrict__ col1,
                                               const int* __restrict__ rp2, const int* __restrict__ pe2,
                                               const int* __restrict__ col2,
                                               const float* __restrict__ d1, const float* __restrict__ d2,
                                               const unsigned short* __restrict__ U1,
                                               const unsigned short* __restrict__ U2,
                                               const float* __restrict__ t1, const float* __restrict__ t2,
                                               unsigned short* __restrict__ p, unsigned short* __restrict__ q,
                                               int n) {
  int t = blockIdx.x * 256 + threadIdx.x;
  int row = t >> 2;
  if (row >= n) return;
  int sub = t & 3;           // 8-element slice of the 32-wide row
  float a1[8] = {0, 0, 0, 0, 0, 0, 0, 0};
  float a2[8] = {0, 0, 0, 0, 0, 0, 0, 0};

  {
    const unsigned short* U = U1;
    int e = rp1[row], end = pe1[row];
    for (; e + 8 <= end; e += 8) {
      int c[8];
#pragma unroll
      for (int j = 0; j < 8; ++j) c[j] = col1[e + j];
      uint4 v[8];
#pragma unroll
      for (int j = 0; j < 8; ++j) v[j] = *(const uint4*)(U + (size_t)c[j] * 32 + sub * 8);
#pragma unroll
      for (int j = 0; j < 8; ++j) {
        a1[0] += bflo(v[j].x); a1[1] += bfhi(v[j].x);
        a1[2] += bflo(v[j].y); a1[3] += bfhi(v[j].y);
        a1[4] += bflo(v[j].z); a1[5] += bfhi(v[j].z);
        a1[6] += bflo(v[j].w); a1[7] += bfhi(v[j].w);
      }
    }
    for (; e < end; ++e) {
      uint4 v = *(const uint4*)(U + (size_t)col1[e] * 32 + sub * 8);
      a1[0] += bflo(v.x); a1[1] += bfhi(v.x);
      a1[2] += bflo(v.y); a1[3] += bfhi(v.y);
      a1[4] += bflo(v.z); a1[5] += bfhi(v.z);
      a1[6] += bflo(v.w); a1[7] += bfhi(v.w);
    }
  }
  {
    const unsigned short* U = U2;
    int e = rp2[row], end = pe2[row];
    for (; e + 8 <= end; e += 8) {
      int c[8];
#pragma unroll
      for (int j = 0; j < 8; ++j) c[j] = col2[e + j];
      uint4 v[8];
#pragma unroll
      for (int j = 0; j < 8; ++j) v[j] = *(const uint4*)(U + (size_t)c[j] * 32 + sub * 8);
#pragma unroll
      for (int j = 0; j < 8; ++j) {
        a2[0] += bflo(v[j].x); a2[1] += bfhi(v[j].x);
        a2[2] += bflo(v[j].y); a2[3] += bfhi(v[j].y);
        a2[4] += bflo(v[j].z); a2[5] += bfhi(v[j].z);
        a2[6] += bflo(v[j].w); a2[7] += bfhi(v[j].w);
      }
    }
    for (; e < end; ++e) {
      uint4 v = *(const uint4*)(U + (size_t)col2[e] * 32 + sub * 8);
      a2[0] += bflo(v.x); a2[1] += bfhi(v.x);
      a2[2] += bflo(v.y); a2[3] += bfhi(v.y);
      a2[4] += bflo(v.z); a2[5] += bfhi(v.z);
      a2[6] += bflo(v.w); a2[7] += bfhi(v.w);
    }
  }

  float s1 = d1[row], s2 = d2[row];
  const float* tb = (sub < 2) ? (t1 + (size_t)row * 16 + sub * 8)
                              : (t2 + (size_t)row * 16 + (sub - 2) * 8);
  unsigned short* dst = (sub < 2) ? (p + (size_t)row * 16 + sub * 8)
                                  : (q + (size_t)row * 16 + (sub - 2) * 8);
  float so = (sub < 2) ? s1 : s2;
  float4 b0 = *(const float4*)tb;
  float4 b1 = *(const float4*)(tb + 4);
  float bb[8] = {b0.x, b0.y, b0.z, b0.w, b1.x, b1.y, b1.z, b1.w};
  u16x8 us;
#pragma unroll
  for (int i = 0; i < 8; ++i) {
    float v = so * (bb[i] + s1 * a1[i] + s2 * a2[i]);
    us[i] = f2bf(v);
  }
  *(u16x8*)dst = us;
}

// ---------------- fused outer passes + log_softmax (8-deep MLP pipeline) ----------------
// z = t0 + d1*sum_{A1} p[c] + d2*sum_{A2} q[c]; out = log_softmax(z)
__global__ __launch_bounds__(256) void k_outer(const int* __restrict__ rp1, const int* __restrict__ pe1,
                                               const int* __restrict__ col1,
                                               const int* __restrict__ rp2, const int* __restrict__ pe2,
                                               const int* __restrict__ col2,
                                               const float* __restrict__ d1, const float* __restrict__ d2,
                                               const unsigned short* __restrict__ p,
                                               const unsigned short* __restrict__ q,
                                               const float* __restrict__ t0, float* __restrict__ out,
                                               int n) {
  int t = blockIdx.x * 256 + threadIdx.x;
  int row = t >> 2;
  if (row >= n) return;
  int sub = t & 3;           // 4-element slice of the 16-wide logits
  float a[4] = {0, 0, 0, 0}, b[4] = {0, 0, 0, 0};

  {
    int e = rp1[row], end = pe1[row];
    for (; e + 8 <= end; e += 8) {
      int c[8];
#pragma unroll
      for (int j = 0; j < 8; ++j) c[j] = col1[e + j];
      uint2 v[8];
#pragma unroll
      for (int j = 0; j < 8; ++j) v[j] = *(const uint2*)(p + (size_t)c[j] * 16 + sub * 4);
#pragma unroll
      for (int j = 0; j < 8; ++j) {
        a[0] += bflo(v[j].x); a[1] += bfhi(v[j].x);
        a[2] += bflo(v[j].y); a[3] += bfhi(v[j].y);
      }
    }
    for (; e < end; ++e) {
      uint2 v = *(const uint2*)(p + (size_t)col1[e] * 16 + sub * 4);
      a[0] += bflo(v.x); a[1] += bfhi(v.x);
      a[2] += bflo(v.y); a[3] += bfhi(v.y);
    }
  }
  {
    int e = rp2[row], end = pe2[row];
    for (; e + 8 <= end; e += 8) {
      int c[8];
#pragma unroll
      for (int j = 0; j < 8; ++j) c[j] = col2[e + j];
      uint2 v[8];
#pragma unroll
      for (int j = 0; j < 8; ++j) v[j] = *(const uint2*)(q + (size_t)c[j] * 16 + sub * 4);
#pragma unroll
      for (int j = 0; j < 8; ++j) {
        b[0] += bflo(v[j].x); b[1] += bfhi(v[j].x);
        b[2] += bflo(v[j].y); b[3] += bfhi(v[j].y);
      }
    }
    for (; e < end; ++e) {
      uint2 v = *(const uint2*)(q + (size_t)col2[e] * 16 + sub * 4);
      b[0] += bflo(v.x); b[1] += bfhi(v.x);
      b[2] += bflo(v.y); b[3] += bfhi(v.y);
    }
  }

  float s1 = d1[row], s2 = d2[row];
  float4 t0v = *(const float4*)(t0 + (size_t)row * 16 + sub * 4);
  float z[4];
  z[0] = t0v.x + s1 * a[0] + s2 * b[0];
  z[1] = t0v.y + s1 * a[1] + s2 * b[1];
  z[2] = t0v.z + s1 * a[2] + s2 * b[2];
  z[3] = t0v.w + s1 * a[3] + s2 * b[3];
  float m = fmaxf(fmaxf(z[0], z[1]), fmaxf(z[2], z[3]));
  m = fmaxf(m, __shfl_xor(m, 1));
  m = fmaxf(m, __shfl_xor(m, 2));
  float s = expf(z[0] - m) + expf(z[1] - m) + expf(z[2] - m) + expf(z[3] - m);
  s += __shfl_xor(s, 1);
  s += __shfl_xor(s, 2);
  float lg = m + logf(s);
  float4 o;
  o.x = z[0] - lg; o.y = z[1] - lg; o.z = z[2] - lg; o.w = z[3] - lg;
  *(float4*)(out + (size_t)row * 16 + sub * 4) = o;
}

extern "C" void kernel_launch(void* const* d_in, const int* in_sizes, int n_in,
                              void* d_out, int out_size, void* d_ws, size_t ws_size,
                              hipStream_t stream) {
  const float* x   = (const float*)d_in[0];
  const int*   a1i = (const int*)d_in[1];
  const int*   a2i = (const int*)d_in[3];
  const float* we  = (const float*)d_in[5];
  const float* wcl = (const float*)d_in[6];
  float* out = (float*)d_out;

  const int n  = in_sizes[0] / NFEAT;
  const int e1 = in_sizes[2];
  const int e2 = in_sizes[4];
  const int nb = (n + 255) / 256;   // <= 512 (requires n <= 131072)

  char* ws = (char*)d_ws;
  size_t off = 0;
  auto alloc = [&](size_t bytes) -> void* {
    void* p = ws + off;
    off += (bytes + 255) & ~(size_t)255;
    return p;
  };
  float* t0 = (float*)alloc((size_t)n * 16 * 4);
  float* t1 = (float*)alloc((size_t)n * 16 * 4);
  float* t2 = (float*)alloc((size_t)n * 16 * 4);
  unsigned short* U1 = (unsigned short*)alloc((size_t)n * 32 * 2);   // bf16
  unsigned short* U2 = (unsigned short*)alloc((size_t)n * 32 * 2);   // bf16
  unsigned short* pp = (unsigned short*)alloc((size_t)n * 16 * 2);   // bf16
  unsigned short* qq = (unsigned short*)alloc((size_t)n * 16 * 2);   // bf16
  int* rp1  = (int*)alloc((size_t)n * 4);
  int* pos1 = (int*)alloc((size_t)n * 4);
  int* rp2  = (int*)alloc((size_t)n * 4);
  int* pos2 = (int*)alloc((size_t)n * 4);
  float* d1 = (float*)alloc((size_t)n * 4);
  float* d2 = (float*)alloc((size_t)n * 4);
  int*      col1 = (int*)alloc((size_t)e1 * 4);
  int*      col2 = (int*)alloc((size_t)e2 * 4);
  unsigned* stg1 = (unsigned*)alloc((size_t)e1 * 4);
  unsigned* stg2 = (unsigned*)alloc((size_t)e2 * 4);
  int* bcnt1 = (int*)alloc(4096);
  int* bcnt2 = (int*)alloc(4096);
  int* bst1  = (int*)alloc(4096);   // nb+1 entries
  int* bst2  = (int*)alloc(4096);
  int* bc1   = (int*)alloc(4096);
  int* bc2   = (int*)alloc(4096);

  (void)ws_size; (void)n_in; (void)out_size;

  hipMemsetAsync(bcnt1, 0, (size_t)nb * 4, stream);
  hipMemsetAsync(bcnt2, 0, (size_t)nb * 4, stream);

  k_bhist<<<(e1 + 4095) / 4096, 256, 0, stream>>>(a1i, bcnt1, e1, nb);
  k_bhist<<<(e2 + 4095) / 4096, 256, 0, stream>>>(a2i, bcnt2, e2, nb);

  k_bscan<<<1, 512, 0, stream>>>(bcnt1, bcnt2, bst1, bst2, bc1, bc2, nb);

  k_bin<<<(e1 + 4095) / 4096, 256, 0, stream>>>(a1i, a1i + e1, bc1, stg1, e1, nb);
  k_bin<<<(e2 + 4095) / 4096, 256, 0, stream>>>(a2i, a2i + e2, bc2, stg2, e2, nb);

  k_debin<<<nb, 256, 0, stream>>>(stg1, bst1, rp1, pos1, d1, col1, n);
  k_debin<<<nb, 256, 0, stream>>>(stg2, bst2, rp2, pos2, d2, col2, n);

  k_embed<<<(n + 63) / 64, 256, 0, stream>>>(x, we, wcl, d1, d2, t0, U1, U2, n);

  k_inner<<<(n * 4 + 255) / 256, 256, 0, stream>>>(rp1, pos1, col1, rp2, pos2, col2,
                                                   d1, d2, U1, U2, t1, t2, pp, qq, n);

  k_outer<<<(n * 4 + 255) / 256, 256, 0, stream>>>(rp1, pos1, col1, rp2, pos2, col2,
                                                   d1, d2, pp, qq, t0, out, n);
}